// Round 2
// baseline (617.743 us; speedup 1.0000x reference)
//
#include <hip/hip_runtime.h>
#include <hip/hip_bf16.h>

#define LL 128
#define BB 32
#define EE 128
#define HH 256
#define NHH 8
#define G3 768   // 3*H
#define IN0 130
#define ETA 100
#define F1 168
#define CLSIN 2304  // 8*256 + 256

typedef _Float16 half_t;
typedef __attribute__((ext_vector_type(2))) _Float16 half2v;
typedef __attribute__((ext_vector_type(16))) unsigned int uint16v;

#if defined(__has_builtin)
#if __has_builtin(__builtin_amdgcn_fdot2)
#define HAVE_FDOT2 1
#endif
#endif

__device__ __forceinline__ float fdot2f(half2v a, half2v b, float c) {
#ifdef HAVE_FDOT2
  return __builtin_amdgcn_fdot2(a, b, c, false);
#else
  return c + (float)a.x * (float)b.x + (float)a.y * (float)b.y;
#endif
}
__device__ __forceinline__ float fdot2u(unsigned int a, unsigned int b, float c) {
  return fdot2f(__builtin_bit_cast(half2v, a), __builtin_bit_cast(half2v, b), c);
}

// LDS-only barrier: skip the compiler's vmcnt(0) drain (no cross-thread
// global-memory dependencies at our barriers).
#define BARRIER_LDS() __asm__ volatile("s_waitcnt lgkmcnt(0)\n\ts_barrier" ::: "memory")

__device__ __forceinline__ float sigmoidf_(float x) { return 1.0f / (1.0f + __expf(-x)); }
__device__ __forceinline__ float tanhf_(float x) { return 1.0f - 2.0f / (__expf(2.0f * x) + 1.0f); }

// ---------------------------------------------------------------------------
// prep: weight repack fp32 -> f16 (weights ~N(0,0.05^2): f16 rel err 5e-4)
// ---------------------------------------------------------------------------
__global__ void prep_kernel(
    const float* __restrict__ Wa0, const float* __restrict__ Wih0,
    const float* __restrict__ Wih1, const float* __restrict__ Whh0,
    const float* __restrict__ Whh1,
    half_t* __restrict__ Wa0Ta, half_t* __restrict__ Wa0Tb,
    half2v* __restrict__ Wih0T2, half2v* __restrict__ Wih1T2,
    half_t* __restrict__ Whh0h, half_t* __restrict__ Whh1h)
{
  int idx = blockIdx.x * blockDim.x + threadIdx.x;
  const int n1 = 16384, n2 = 16384, n3 = 65 * 768, n4 = 128 * 768, n5 = 196608;
  if (idx < n1) {
    int d = idx >> 7, k = idx & 127;
    Wa0Ta[idx] = (half_t)Wa0[k * 256 + d];
  } else if ((idx -= n1) < n2) {
    int d = idx >> 7, k = idx & 127;
    Wa0Tb[idx] = (half_t)Wa0[k * 256 + 128 + d];
  } else if ((idx -= n2) < n3) {
    int d2 = idx / 768, r = idx % 768;
    half2v w; w.x = (half_t)Wih0[r * IN0 + 2 * d2]; w.y = (half_t)Wih0[r * IN0 + 2 * d2 + 1];
    Wih0T2[idx] = w;
  } else if ((idx -= n3) < n4) {
    int d2 = idx / 768, r = idx % 768;
    half2v w; w.x = (half_t)Wih1[r * HH + 2 * d2]; w.y = (half_t)Wih1[r * HH + 2 * d2 + 1];
    Wih1T2[idx] = w;
  } else if ((idx -= n4) < n5) {
    Whh0h[idx] = (half_t)Whh0[idx];
  } else if ((idx -= n5) < n5) {
    Whh1h[idx] = (half_t)Whh1[idx];
  }
}

// ---------------------------------------------------------------------------
// embed gather + U/V factors of the pairwise attention
// ---------------------------------------------------------------------------
__global__ void embed_uv_kernel(
    const int* __restrict__ node,             // [L*B]
    const float* __restrict__ table,          // [20001][128]
    const half_t* __restrict__ Wa0Ta,         // [128 d][128 k]
    const half_t* __restrict__ Wa0Tb,
    const float* __restrict__ ba0,            // [128]
    half2v* __restrict__ e_h2,                // [L*B][64]
    float* __restrict__ U,
    float* __restrict__ V)
{
  int lb = blockIdx.x;
  int k = threadIdx.x;  // 128
  __shared__ float es[EE];
  int n = node[lb];
  float ev = table[(size_t)n * EE + k];
  es[k] = ev;
  __syncthreads();
  if (k < 64) {
    half2v p; p.x = (half_t)es[2 * k]; p.y = (half_t)es[2 * k + 1];
    e_h2[(size_t)lb * 64 + k] = p;
  }
  float u = 0.f, v = ba0[k];
  #pragma unroll 8
  for (int d = 0; d < EE; ++d) {
    float x = es[d];
    u += (float)Wa0Ta[d * EE + k] * x;
    v += (float)Wa0Tb[d * EE + k] * x;
  }
  U[(size_t)lb * EE + k] = u;
  V[(size_t)lb * EE + k] = v;
}

// ---------------------------------------------------------------------------
// w_pre[i,b,h] = sum_j sum_k Wa1[h,k] * relu(U[j,b,k]+V[i,b,k]) + L*ba1[h]
// ---------------------------------------------------------------------------
__global__ __launch_bounds__(128) void attn_w_kernel(
    const float* __restrict__ U, const float* __restrict__ V,
    const float* __restrict__ Wa1,  // [8][128]
    const float* __restrict__ ba1,  // [8]
    float* __restrict__ wpre)       // [L][B][8]
{
  int ig = blockIdx.x >> 5;
  int b = blockIdx.x & 31;
  int i0 = ig * 4;
  int k = threadIdx.x;  // 128
  float vk[4];
  #pragma unroll
  for (int ii = 0; ii < 4; ++ii) vk[ii] = V[((size_t)(i0 + ii) * BB + b) * EE + k];
  float wa[NHH], acc[4][NHH];
  #pragma unroll
  for (int h = 0; h < NHH; ++h) wa[h] = Wa1[h * EE + k];
  #pragma unroll
  for (int ii = 0; ii < 4; ++ii)
    #pragma unroll
    for (int h = 0; h < NHH; ++h) acc[ii][h] = 0.f;
  for (int j = 0; j < LL; ++j) {
    float u = U[((size_t)j * BB + b) * EE + k];
    #pragma unroll
    for (int ii = 0; ii < 4; ++ii) {
      float tv = fmaxf(u + vk[ii], 0.f);
      #pragma unroll
      for (int h = 0; h < NHH; ++h) acc[ii][h] += wa[h] * tv;
    }
  }
  __shared__ float part[2][32];
  int wave = k >> 6, lane = k & 63;
  #pragma unroll
  for (int ii = 0; ii < 4; ++ii)
    #pragma unroll
    for (int h = 0; h < NHH; ++h) {
      float a = acc[ii][h];
      #pragma unroll
      for (int off = 32; off > 0; off >>= 1) a += __shfl_xor(a, off, 64);
      if (lane == 0) part[wave][ii * 8 + h] = a;
    }
  __syncthreads();
  if (k < 32) {
    int ii = k >> 3, h = k & 7;
    float w = part[0][k] + part[1][k] + (float)LL * ba1[h];
    wpre[((size_t)(i0 + ii) * BB + b) * NHH + h] = w;
  }
}

// softmax over l of (w * mask): masked entries become 0 and STAY in the softmax
__global__ void attn_softmax_kernel(
    const float* __restrict__ wpre, const int* __restrict__ slen,
    float* __restrict__ wsoft)
{
  int b = blockIdx.x >> 3;
  int h = blockIdx.x & 7;
  int l = threadIdx.x;  // 128
  int len = slen[b];
  float x = wpre[((size_t)l * BB + b) * NHH + h];
  float xv = (l < len) ? x : 0.f;
  float m = xv;
  #pragma unroll
  for (int off = 32; off > 0; off >>= 1) m = fmaxf(m, __shfl_xor(m, off, 64));
  __shared__ float sm[2], ss[2];
  int wave = l >> 6;
  if ((l & 63) == 0) sm[wave] = m;
  __syncthreads();
  m = fmaxf(sm[0], sm[1]);
  float e = __expf(xv - m);
  float s = e;
  #pragma unroll
  for (int off = 32; off > 0; off >>= 1) s += __shfl_xor(s, off, 64);
  if ((l & 63) == 0) ss[wave] = s;
  __syncthreads();
  s = ss[0] + ss[1];
  wsoft[((size_t)l * BB + b) * NHH + h] = e / s;
}

// ---------------------------------------------------------------------------
// gi0: [e, ts] @ Wih0.T + bih0, 8 lb per block, v_dot2 on packed pairs
// ---------------------------------------------------------------------------
__global__ __launch_bounds__(256) void gi0_kernel(
    const half2v* __restrict__ e_h2, const float* __restrict__ ts,
    const half2v* __restrict__ W2,   // [65][768]
    const float* __restrict__ bih,
    float* __restrict__ gi)
{
  int lb0 = blockIdx.x * 8;
  int tid = threadIdx.x;  // 256
  __shared__ half2v xs2[8][66];
  for (int idx = tid; idx < 512; idx += 256) {
    int q = idx >> 6, d2 = idx & 63;
    xs2[q][d2] = e_h2[(size_t)(lb0 + q) * 64 + d2];
  }
  if (tid < 8) {
    half2v t2; t2.x = (half_t)ts[(lb0 + tid) * 2]; t2.y = (half_t)ts[(lb0 + tid) * 2 + 1];
    xs2[tid][64] = t2;
  }
  __syncthreads();
  float acc[8][3];
  #pragma unroll
  for (int q = 0; q < 8; ++q) { acc[q][0] = 0.f; acc[q][1] = 0.f; acc[q][2] = 0.f; }
  for (int d2 = 0; d2 < 65; ++d2) {
    half2v w0 = W2[d2 * 768 + tid];
    half2v w1 = W2[d2 * 768 + 256 + tid];
    half2v w2 = W2[d2 * 768 + 512 + tid];
    #pragma unroll
    for (int q = 0; q < 8; ++q) {
      half2v x = xs2[q][d2];
      acc[q][0] = fdot2f(w0, x, acc[q][0]);
      acc[q][1] = fdot2f(w1, x, acc[q][1]);
      acc[q][2] = fdot2f(w2, x, acc[q][2]);
    }
  }
  float b0 = bih[tid], b1 = bih[256 + tid], b2 = bih[512 + tid];
  #pragma unroll
  for (int q = 0; q < 8; ++q) {
    float* gp = gi + (size_t)(lb0 + q) * G3;
    gp[tid] = acc[q][0] + b0; gp[256 + tid] = acc[q][1] + b1; gp[512 + tid] = acc[q][2] + b2;
  }
}

// ---------------------------------------------------------------------------
// gi1: out0 @ Wih1.T + bih1, 8 lb per block
// ---------------------------------------------------------------------------
__global__ __launch_bounds__(256) void gi1_kernel(
    const float* __restrict__ out0,  // [L*B][256]
    const half2v* __restrict__ W2,   // [128][768]
    const float* __restrict__ bih,
    float* __restrict__ gi)
{
  int lb0 = blockIdx.x * 8;
  int tid = threadIdx.x;  // 256
  __shared__ half2v xs2[8][128];
  for (int idx = tid; idx < 1024; idx += 256) {
    int q = idx >> 7, d2 = idx & 127;
    float2 v = ((const float2*)(out0 + (size_t)(lb0 + q) * HH))[d2];
    half2v x; x.x = (half_t)v.x; x.y = (half_t)v.y;
    xs2[q][d2] = x;
  }
  __syncthreads();
  float acc[8][3];
  #pragma unroll
  for (int q = 0; q < 8; ++q) { acc[q][0] = 0.f; acc[q][1] = 0.f; acc[q][2] = 0.f; }
  for (int d2 = 0; d2 < 128; ++d2) {
    half2v w0 = W2[d2 * 768 + tid];
    half2v w1 = W2[d2 * 768 + 256 + tid];
    half2v w2 = W2[d2 * 768 + 512 + tid];
    #pragma unroll
    for (int q = 0; q < 8; ++q) {
      half2v x = xs2[q][d2];
      acc[q][0] = fdot2f(w0, x, acc[q][0]);
      acc[q][1] = fdot2f(w1, x, acc[q][1]);
      acc[q][2] = fdot2f(w2, x, acc[q][2]);
    }
  }
  float b0 = bih[tid], b1 = bih[256 + tid], b2 = bih[512 + tid];
  #pragma unroll
  for (int q = 0; q < 8; ++q) {
    float* gp = gi + (size_t)(lb0 + q) * G3;
    gp[tid] = acc[q][0] + b0; gp[256 + tid] = acc[q][1] + b1; gp[512 + tid] = acc[q][2] + b2;
  }
}

// ---------------------------------------------------------------------------
// GRU scan v2: one block per batch element, 512 threads.
// Thread (g = tid>>2, s = tid&3) holds the SIX rows
//   {2g, 2g+1, 256+2g, 256+2g+1, 512+2g, 512+2g+1}   (units 2g,2g+1 x 3 gates)
// restricted to k-slice [64s, 64s+64), as 12 x uint16 vectors = 192 VGPRs.
// The 4-lane group 4g..4g+3 therefore owns units {2g, 2g+1} COMPLETELY:
// a 2-step shfl_xor butterfly (masks 1,2) finishes all six dot products
// in-register — no p5 LDS partials, no half-block-idle reduce phase.
// h is double-buffered in LDS -> ONE barrier per step (was two).
// The "+v" residency pin runs once per 4 unrolled steps to amortize any
// allocator copy traffic it induces.
// ---------------------------------------------------------------------------
__global__ __launch_bounds__(512, 2) void gru_scan_kernel(
    const half_t* __restrict__ Whhh,         // [768][256] f16
    const float* __restrict__ bhh,           // [768]
    const float* __restrict__ gi,            // [L][B][768]
    const int* __restrict__ slen,            // [B]
    float* __restrict__ out,                 // [L][B][256]
    float* __restrict__ hT)                  // [B][256]
{
  const int b = blockIdx.x;
  const int tid = threadIdx.x;
  const int s = tid & 3;
  const int g = tid >> 2;
  // two h buffers: 4 k-regions x (8 data + 1 pad) uint4 each (pad: the 4
  // same-bank region starts would otherwise 4-way conflict on ds_read_b128)
  __shared__ __align__(16) uint4 hbuf[2][4 * 9];

  uint16v W[12];
  #pragma unroll
  for (int rr = 0; rr < 6; ++rr) {
    int row = ((rr >> 1) << 8) + 2 * g + (rr & 1);
    const uint4* wp = (const uint4*)(Whhh + (size_t)row * HH + 64 * s);
    #pragma unroll
    for (int j = 0; j < 8; ++j) {
      uint4 v = wp[j];
      int base = 4 * j;  // 0,4,...,28 — constant after unroll
      if (base < 16) {
        W[2 * rr][base] = v.x; W[2 * rr][base + 1] = v.y;
        W[2 * rr][base + 2] = v.z; W[2 * rr][base + 3] = v.w;
      } else {
        W[2 * rr + 1][base - 16] = v.x; W[2 * rr + 1][base - 15] = v.y;
        W[2 * rr + 1][base - 14] = v.z; W[2 * rr + 1][base - 13] = v.w;
      }
    }
  }

  const int len = slen[b];
  const int u = 2 * g + (s & 1);  // owned unit (meaningful for s < 2)
  float bhr = 0.f, bhz = 0.f, bhn = 0.f, hold = 0.f;
  if (s < 2) {
    bhr = bhh[u]; bhz = bhh[HH + u]; bhn = bhh[2 * HH + u];
  }
  for (int i = tid; i < 72; i += 512) {
    uint4 z; z.x = z.y = z.z = z.w = 0u; ((uint4*)hbuf)[i] = z;
  }
  __syncthreads();

  const float* gib = gi + (size_t)b * G3;
  float* outb = out + (size_t)b * HH;

  #pragma unroll 1
  for (int t4 = 0; t4 < LL / 4; ++t4) {
    // pin all 12 weight vectors live once per 4 steps
    __asm__ volatile(""
        : "+v"(W[0]), "+v"(W[1]), "+v"(W[2]), "+v"(W[3]), "+v"(W[4]),
          "+v"(W[5]), "+v"(W[6]), "+v"(W[7]), "+v"(W[8]), "+v"(W[9]),
          "+v"(W[10]), "+v"(W[11]));
    #pragma unroll
    for (int tt = 0; tt < 4; ++tt) {
      const int t = 4 * t4 + tt;
      const uint4* rb = hbuf[t & 1];
      uint4* wb = (uint4*)hbuf[(t & 1) ^ 1];
      float g0 = 0.f, g1 = 0.f, g2 = 0.f;
      if (s < 2) {
        const float* gp = gib + (size_t)t * (BB * G3);
        g0 = gp[u]; g1 = gp[HH + u]; g2 = gp[2 * HH + u];
      }
      float acc[6] = {0.f, 0.f, 0.f, 0.f, 0.f, 0.f};
      #pragma unroll
      for (int c = 0; c < 4; ++c) {
        uint4 ha = rb[s * 9 + 2 * c];
        uint4 hb = rb[s * 9 + 2 * c + 1];
        unsigned int hu[8] = {ha.x, ha.y, ha.z, ha.w, hb.x, hb.y, hb.z, hb.w};
        #pragma unroll
        for (int rr = 0; rr < 6; ++rr) {
          #pragma unroll
          for (int i = 0; i < 8; ++i) {
            int idx = 8 * c + i;  // constant after unroll
            unsigned int wv = (idx < 16) ? W[2 * rr][idx] : W[2 * rr + 1][idx - 16];
            acc[rr] = fdot2u(wv, hu[i], acc[rr]);
          }
        }
      }
      // 4-lane butterfly: every lane of the group gets all six full sums
      #pragma unroll
      for (int rr = 0; rr < 6; ++rr) {
        acc[rr] += __shfl_xor(acc[rr], 1, 64);
        acc[rr] += __shfl_xor(acc[rr], 2, 64);
      }
      float rs = (s & 1) ? acc[1] : acc[0];
      float zsum = (s & 1) ? acc[3] : acc[2];
      float ns = (s & 1) ? acc[5] : acc[4];
      float r_ = sigmoidf_(g0 + rs + bhr);
      float z_ = sigmoidf_(g1 + zsum + bhz);
      float n_ = tanhf_(g2 + r_ * (ns + bhn));
      float hnew = (1.f - z_) * n_ + z_ * hold;
      bool valid = t < len;
      hold = valid ? hnew : hold;
      if (s < 2) {
        ((half_t*)(wb + (u >> 6) * 9))[u & 63] = (half_t)hold;
        outb[(size_t)t * (BB * HH) + u] = valid ? hnew : 0.f;
      }
      BARRIER_LDS();
    }
  }
  if (s < 2) hT[(size_t)b * HH + u] = hold;
}

// ---------------------------------------------------------------------------
// ctx[b, h*256+d] = sum_l wsoft[l,b,h] * out1[l,b,d]
// ---------------------------------------------------------------------------
__global__ void ctx_kernel(
    const float* __restrict__ wsoft, const float* __restrict__ out1,
    float* __restrict__ ctx)
{
  int b = blockIdx.x >> 3, h = blockIdx.x & 7;
  int d = threadIdx.x;  // 256
  float acc = 0.f;
  for (int l = 0; l < LL; ++l) {
    float w = wsoft[((size_t)l * BB + b) * NHH + h];
    acc += w * out1[((size_t)l * BB + b) * HH + d];
  }
  ctx[(size_t)b * (NHH * HH) + h * HH + d] = acc;
}

// ---------------------------------------------------------------------------
// final MLP: z = selu([ctx, hT] @ Wf0.T + bf0); logits = z @ Wf1.T + bf1;
// out = log_softmax(logits)
// ---------------------------------------------------------------------------
__global__ __launch_bounds__(512) void final_kernel(
    const float* __restrict__ ctx, const float* __restrict__ hT,
    const float* __restrict__ Wf0,   // [168][2304]
    const float* __restrict__ bf0,
    const float* __restrict__ Wf1,   // [100][168]
    const float* __restrict__ bf1,
    float* __restrict__ outp)        // [B][100]
{
  int b = blockIdx.x;
  int tid = threadIdx.x;
  int wave = tid >> 6, lane = tid & 63;
  __shared__ float4 xs4[CLSIN / 4];
  __shared__ float zs[F1];
  __shared__ float ls[ETA];
  float* xs = (float*)xs4;
  for (int i = tid; i < NHH * HH; i += 512) xs[i] = ctx[(size_t)b * (NHH * HH) + i];
  if (tid < HH) xs[NHH * HH + tid] = hT[(size_t)b * HH + tid];
  __syncthreads();
  for (int r = wave; r < F1; r += 8) {
    const float4* wp = (const float4*)(Wf0 + (size_t)r * CLSIN);
    float acc = 0.f;
    #pragma unroll
    for (int i = 0; i < CLSIN / 4 / 64; ++i) {  // 9
      float4 w = wp[lane + 64 * i];
      float4 x = xs4[lane + 64 * i];
      acc += w.x * x.x + w.y * x.y + w.z * x.z + w.w * x.w;
    }
    #pragma unroll
    for (int off = 32; off > 0; off >>= 1) acc += __shfl_xor(acc, off, 64);
    if (lane == 0) {
      float x = acc + bf0[r];
      const float alpha = 1.6732632423543772f, scale = 1.0507009873554805f;
      zs[r] = scale * (x > 0.f ? x : alpha * (__expf(x) - 1.f));
    }
  }
  __syncthreads();
  for (int r = wave; r < ETA; r += 8) {
    float acc = 0.f;
    for (int k = lane; k < F1; k += 64) acc += Wf1[r * F1 + k] * zs[k];
    #pragma unroll
    for (int off = 32; off > 0; off >>= 1) acc += __shfl_xor(acc, off, 64);
    if (lane == 0) ls[r] = acc + bf1[r];
  }
  __syncthreads();
  if (wave == 0) {
    float v0 = (lane < ETA) ? ls[lane] : -1e30f;
    float v1 = (lane + 64 < ETA) ? ls[lane + 64] : -1e30f;
    float m = fmaxf(v0, v1);
    #pragma unroll
    for (int off = 32; off > 0; off >>= 1) m = fmaxf(m, __shfl_xor(m, off, 64));
    float s = __expf(v0 - m) + __expf(v1 - m);
    #pragma unroll
    for (int off = 32; off > 0; off >>= 1) s += __shfl_xor(s, off, 64);
    float lse = m + __logf(s);
    if (lane < ETA) outp[(size_t)b * ETA + lane] = v0 - lse;
    if (lane + 64 < ETA) outp[(size_t)b * ETA + lane + 64] = v1 - lse;
  }
}

extern "C" void kernel_launch(void* const* d_in, const int* in_sizes, int n_in,
                              void* d_out, int out_size, void* d_ws, size_t ws_size,
                              hipStream_t stream) {
  const int*   node  = (const int*)d_in[0];
  const float* ts    = (const float*)d_in[1];
  const int*   slen  = (const int*)d_in[2];
  const float* table = (const float*)d_in[3];
  const float* Wih0  = (const float*)d_in[4];
  const float* Whh0  = (const float*)d_in[5];
  const float* bih0  = (const float*)d_in[6];
  const float* bhh0  = (const float*)d_in[7];
  const float* Wih1  = (const float*)d_in[8];
  const float* Whh1  = (const float*)d_in[9];
  const float* bih1  = (const float*)d_in[10];
  const float* bhh1  = (const float*)d_in[11];
  const float* Wa0   = (const float*)d_in[12];
  const float* ba0   = (const float*)d_in[13];
  const float* Wa1   = (const float*)d_in[14];
  const float* ba1   = (const float*)d_in[15];
  const float* Wf0   = (const float*)d_in[16];
  const float* bf0   = (const float*)d_in[17];
  const float* Wf1   = (const float*)d_in[18];
  const float* bf1   = (const float*)d_in[19];

  char* ws = (char*)d_ws;
  size_t off = 0;
  auto alloc = [&](size_t n) { void* p = (void*)(ws + off); off += (n + 255) & ~(size_t)255; return p; };

  half2v* e_h2 = (half2v*)alloc((size_t)LL * BB * 64 * 4);
  float* U     = (float*)alloc((size_t)LL * BB * EE * 4);
  float* V     = (float*)alloc((size_t)LL * BB * EE * 4);
  float* gi    = (float*)alloc((size_t)LL * BB * G3 * 4);   // reused for both layers
  float* out0  = (float*)alloc((size_t)LL * BB * HH * 4);
  float* out1  = (float*)alloc((size_t)LL * BB * HH * 4);
  float* hTb   = (float*)alloc((size_t)BB * HH * 4);
  float* wpre  = (float*)alloc((size_t)LL * BB * NHH * 4);
  float* wsoft = (float*)alloc((size_t)LL * BB * NHH * 4);
  float* ctxb  = (float*)alloc((size_t)BB * NHH * HH * 4);
  half_t* Wa0Ta = (half_t*)alloc((size_t)128 * 128 * 2);
  half_t* Wa0Tb = (half_t*)alloc((size_t)128 * 128 * 2);
  half2v* Wih0T2 = (half2v*)alloc((size_t)65 * 768 * 4);
  half2v* Wih1T2 = (half2v*)alloc((size_t)128 * 768 * 4);
  half_t* Whh0h = (half_t*)alloc((size_t)G3 * HH * 2);
  half_t* Whh1h = (half_t*)alloc((size_t)G3 * HH * 2);
  if (off > ws_size) return;  // workspace too small: fail visibly

  const int prep_total = 16384 + 16384 + 65 * 768 + 128 * 768 + 196608 + 196608;
  prep_kernel<<<(prep_total + 255) / 256, 256, 0, stream>>>(
      Wa0, Wih0, Wih1, Whh0, Whh1, Wa0Ta, Wa0Tb, Wih0T2, Wih1T2, Whh0h, Whh1h);
  embed_uv_kernel<<<LL * BB, 128, 0, stream>>>(node, table, Wa0Ta, Wa0Tb, ba0, e_h2, U, V);
  attn_w_kernel<<<(LL / 4) * BB, 128, 0, stream>>>(U, V, Wa1, ba1, wpre);
  attn_softmax_kernel<<<BB * NHH, 128, 0, stream>>>(wpre, slen, wsoft);
  gi0_kernel<<<LL * BB / 8, 256, 0, stream>>>(e_h2, ts, Wih0T2, bih0, gi);
  gru_scan_kernel<<<BB, 512, 0, stream>>>(Whh0h, bhh0, gi, slen, out0, hTb);
  gi1_kernel<<<LL * BB / 8, 256, 0, stream>>>(out0, Wih1T2, bih1, gi);
  gru_scan_kernel<<<BB, 512, 0, stream>>>(Whh1h, bhh1, gi, slen, out1, hTb);
  ctx_kernel<<<BB * NHH, 256, 0, stream>>>(wsoft, out1, ctxb);
  final_kernel<<<BB, 512, 0, stream>>>(ctxb, hTb, Wf0, bf0, Wf1, bf1, (float*)d_out);
}